// Round 16
// baseline (139.216 us; speedup 1.0000x reference)
//
#include <hip/hip_runtime.h>
#include <hip/hip_bf16.h>
#include <math.h>

// OmniAttentionMechanism: flex-attention, mixed t2i/lm/mmu mask.
// B=6 (b0,b1: t2i pe=80/100; b2,b3: lm; b4,b5: mmu kv<1027), H=16, S=1280, D=64. fp32 I/O.
//
// Round 16: ZERO-SYNC all-register waves.
//   R15 counters: occupancy pinned ~19%, no pipe >36%, per-wave chains coupled by
//   2 block-wide syncs/tile. K is consumed as PER-LANE A-fragments (swapped QK^T)
//   -> LDS unnecessary. Load K and V fragments direct global->reg from prepacked
//   bf16 Kb/Vtb. No __shared__, no barriers, no vmcnt ledger, no bank conflicts.
//   Waves free-run their own tile lists (wave-level skip); L1 (32KB) gives
//   cross-wave reuse of the 8KB K/V tiles. ~130 VGPR -> ~4 waves/SIMD.
//   Verified core (mask algebra, fragments, permlane, no-max exp2) unchanged.

#define SS 1280
#define DD 64
#define NH 16
#define TK 64
#define QB 128
#define NITEMS 960

typedef __attribute__((ext_vector_type(8))) short bf16x8;
typedef __attribute__((ext_vector_type(16))) float f32x16;

union UA { uint u[4]; bf16x8 v; };

__device__ inline uint pk2(float a, float b) {
    union { __hip_bfloat162 h; uint u; } cv;
    cv.h = __float22bfloat162_rn(float2{a, b});   // v_cvt_pk_bf16_f32
    return cv.u;
}

__device__ inline void pl32(uint& a, uint& b) {
    asm volatile("v_permlane32_swap_b32 %0, %1" : "+v"(a), "+v"(b));
}

// longest-first static item order
__device__ inline void decode_item(int i, int& b, int& h, int& qt) {
    if (i < 96)  { qt = 9; b = i / 16; h = i % 16; return; }                   // N=20
    i -= 96;
    if (i < 256) { b = i / 128; qt = 1 + (i % 128) / 16; h = i % 16; return; } // t2i qt1-8, N=18
    i -= 256;
    if (i < 32)  { b = 2 + i / 16; qt = 8; h = i % 16; return; }               // lm qt8, N=18
    i -= 32;
    if (i < 32)  { b = 4 + i / 16; qt = 8; h = i % 16; return; }               // mmu qt8, N=18
    i -= 32;
    if (i < 256) { b = 4 + i / 128; qt = (i % 128) / 16; h = i % 16; return; } // mmu qt0-7, N=17
    i -= 256;
    if (i < 224) { qt = 7 - i / 32; b = 2 + (i % 32) / 16; h = i % 16; return; } // lm qt7..1
    i -= 224;
    if (i < 32)  { b = 2 + i / 16; qt = 0; h = i % 16; return; }               // lm qt0, N=2
    i -= 32;
    b = i / 16; qt = 0; h = i % 16;                                            // t2i qt0, N=2
}

// ============ fused prepass: K->bf16 (gx<3840) | V->Vt[d][kv] bf16 (gx>=3840) ============
__global__ __launch_bounds__(256) void prepass8(
    const float* __restrict__ K, const float* __restrict__ V,
    ushort* __restrict__ Kb, ushort* __restrict__ Vtb)
{
    const int gx = blockIdx.x;
    const int t  = threadIdx.x;
    if (gx < 3840) {
        const size_t e = ((size_t)gx * 256 + t) * 8;
        const float4 a = *(const float4*)(K + e);
        const float4 c = *(const float4*)(K + e + 4);
        UA u;
        u.u[0] = pk2(a.x, a.y); u.u[1] = pk2(a.z, a.w);
        u.u[2] = pk2(c.x, c.y); u.u[3] = pk2(c.z, c.w);
        *(bf16x8*)(Kb + e) = u.v;
    } else {
        const int g   = gx - 3840;
        const int kvt = g % 20;
        const int p   = g / 20;
        __shared__ float T[64 * 67];
#pragma unroll
        for (int i = 0; i < 16; ++i) {
            const int idx = t + 256 * i;
            T[(idx >> 6) * 67 + (idx & 63)] = V[(size_t)p * (SS * DD) + (size_t)(kvt * 64) * DD + idx];
        }
        __syncthreads();
        ushort* dst = Vtb + (size_t)p * (DD * SS) + kvt * 64;
#pragma unroll
        for (int i = 0; i < 2; ++i) {
            const int c0 = t + 256 * i;
            const int d = c0 >> 3, kc = c0 & 7;
            UA u;
#pragma unroll
            for (int j = 0; j < 4; ++j)
                u.u[j] = pk2(T[(kc * 8 + 2 * j) * 67 + d], T[(kc * 8 + 2 * j + 1) * 67 + d]);
            *(bf16x8*)(dst + (size_t)d * SS + kc * 8) = u.v;
        }
    }
}

// ============================ main attention kernel ============================
__global__ __launch_bounds__(256) void omni_attn16(
    const float* __restrict__ Q, const ushort* __restrict__ Kb,
    const ushort* __restrict__ Vtb, float* __restrict__ O)
{
    int b, h, qt;
    decode_item(blockIdx.x, b, h, qt);     // longest-first dispatch order

    const int t   = threadIdx.x;
    const int w   = t >> 6;
    const int l   = t & 63;
    const int l31 = l & 31;
    const int hi2 = l >> 5;

    const int p   = b * NH + h;
    const int qb0 = qt * QB;
    const int qw0 = qb0 + w * 32;
    const int qr  = qw0 + l31;
    const size_t pbase = (size_t)p * (SS * DD);

    const int bt = (b < 2) ? 0 : (b < 4) ? 1 : 2;
    const int pe = (b == 0) ? 80 : (b == 1) ? 100 : 0;
    const int qmax_w = qw0 + 31;
    const bool w_img = (qw0 >= 128) && (qw0 < 1152);

    const float scale = 0.125f * 1.44269504088896340736f;

    // ---- Q fragments, scale folded in (p = exp2(K·(Q*scale))) ----
    bf16x8 qf[4];
#pragma unroll
    for (int ks = 0; ks < 4; ++ks) {
        const float* src = Q + pbase + (size_t)qr * DD + ks * 16 + hi2 * 8;
        const float4 a = *(const float4*)(src);
        const float4 c = *(const float4*)(src + 4);
        UA u;
        u.u[0] = pk2(a.x * scale, a.y * scale); u.u[1] = pk2(a.z * scale, a.w * scale);
        u.u[2] = pk2(c.x * scale, c.y * scale); u.u[3] = pk2(c.z * scale, c.w * scale);
        qf[ks] = u.v;
    }

    f32x16 o_acc[2];
#pragma unroll
    for (int ntd = 0; ntd < 2; ++ntd)
#pragma unroll
        for (int r = 0; r < 16; ++r) o_acc[ntd][r] = 0.f;
    float psum = 0.f;

    // per-lane fragment bases
    // K A-frag: row (k0+nt*32+l31), elems ksd*16 + hi2*8 .. +7
    const ushort* kfb = Kb + pbase + (size_t)l31 * DD + hi2 * 8;
    // V B-frag: d rows l31 / 32+l31, kv cols (k0+nt*32) + {0,16} + hi2*8
    const ushort* vr0 = Vtb + pbase + (size_t)l31 * SS + hi2 * 8;
    const ushort* vr1 = vr0 + 32 * SS;

    auto need_w_f = [&](int k0) -> bool {
        if (bt == 0) return (k0 <= qmax_w) || (w_img && k0 >= 128 && k0 < 1152);
        if (bt == 1) return (k0 <= qmax_w);
        return (k0 <= qmax_w) || (k0 < 1027);
    };

    int k0 = 0;                            // diagonal tile always needed
    while (k0 < SS) {
        bool full_w;
        if (bt == 0)      full_w = ((k0 >= pe) && (k0 + 63 <= qw0)) || (w_img && k0 >= 128 && k0 < 1152);
        else if (bt == 1) full_w = (k0 + 63 <= qw0);
        else              full_w = (k0 + 63 <= qw0) || (k0 + 63 < 1027);

#pragma unroll
        for (int nt = 0; nt < 2; ++nt) {
            const int kvb_ = k0 + nt * 32;

            // ---- K + V fragments: direct global->reg (K first, V rides behind) ----
            const ushort* kp = kfb + (size_t)kvb_ * DD;
            const bf16x8 kf0 = *(const bf16x8*)(kp);
            const bf16x8 kf1 = *(const bf16x8*)(kp + 16);
            const bf16x8 kf2 = *(const bf16x8*)(kp + 32);
            const bf16x8 kf3 = *(const bf16x8*)(kp + 48);
            const bf16x8 vf0 = *(const bf16x8*)(vr0 + kvb_);
            const bf16x8 vf1 = *(const bf16x8*)(vr0 + kvb_ + 16);
            const bf16x8 vf2 = *(const bf16x8*)(vr1 + kvb_);
            const bf16x8 vf3 = *(const bf16x8*)(vr1 + kvb_ + 16);

            // ---- QK^T swapped: S[kv][q], A = K rows, B = Q cols ----
            f32x16 s;
#pragma unroll
            for (int r = 0; r < 16; ++r) s[r] = 0.f;
            __builtin_amdgcn_s_setprio(1);
            s = __builtin_amdgcn_mfma_f32_32x32x16_bf16(kf0, qf[0], s, 0, 0, 0);
            s = __builtin_amdgcn_mfma_f32_32x32x16_bf16(kf1, qf[1], s, 0, 0, 0);
            s = __builtin_amdgcn_mfma_f32_32x32x16_bf16(kf2, qf[2], s, 0, 0, 0);
            s = __builtin_amdgcn_mfma_f32_32x32x16_bf16(kf3, qf[3], s, 0, 0, 0);
            __builtin_amdgcn_s_setprio(0);

            // ---- mask + exp2 (scale pre-folded) ----
            uint c[8];
#pragma unroll
            for (int i = 0; i < 8; ++i) {
                float pa, pb;
                if (full_w) {
                    pa = __builtin_amdgcn_exp2f(s[2 * i]);
                    pb = __builtin_amdgcn_exp2f(s[2 * i + 1]);
                } else {
                    const int r0i = 2 * i, r1i = 2 * i + 1;
                    const int kva = kvb_ + (r0i & 3) + 8 * (r0i >> 2) + 4 * hi2;
                    const int kvb2 = kvb_ + (r1i & 3) + 8 * (r1i >> 2) + 4 * hi2;
                    bool aa, ab;
                    if (bt == 0) {
                        aa = (qr == kva) | ((kva >= pe) & (qr >= kva)) |
                             ((qr >= 128) & (qr < 1152) & (kva >= 128) & (kva < 1152));
                        ab = (qr == kvb2) | ((kvb2 >= pe) & (qr >= kvb2)) |
                             ((qr >= 128) & (qr < 1152) & (kvb2 >= 128) & (kvb2 < 1152));
                    } else if (bt == 1) {
                        aa = (qr >= kva); ab = (qr >= kvb2);
                    } else {
                        aa = (qr >= kva) | (kva < 1027);
                        ab = (qr >= kvb2) | (kvb2 < 1027);
                    }
                    pa = aa ? __builtin_amdgcn_exp2f(s[2 * i]) : 0.f;
                    pb = ab ? __builtin_amdgcn_exp2f(s[2 * i + 1]) : 0.f;
                }
                psum += pa + pb;
                c[i] = pk2(pa, pb);
            }

            // ---- P half-exchange: 4x v_permlane32_swap ----
            UA A0, A1;
            {
                uint a0 = c[0], b0 = c[2]; pl32(a0, b0);
                uint a1 = c[1], b1 = c[3]; pl32(a1, b1);
                A0.u[0] = a0; A0.u[1] = a1; A0.u[2] = b0; A0.u[3] = b1;
                uint a2 = c[4], b2 = c[6]; pl32(a2, b2);
                uint a3 = c[5], b3 = c[7]; pl32(a3, b3);
                A1.u[0] = a2; A1.u[1] = a3; A1.u[2] = b2; A1.u[3] = b3;
            }

            // ---- PV: o[q][d] += P * V ; B-frags from V registers ----
            __builtin_amdgcn_s_setprio(1);
            o_acc[0] = __builtin_amdgcn_mfma_f32_32x32x16_bf16(A0.v, vf0, o_acc[0], 0, 0, 0);
            o_acc[0] = __builtin_amdgcn_mfma_f32_32x32x16_bf16(A1.v, vf1, o_acc[0], 0, 0, 0);
            o_acc[1] = __builtin_amdgcn_mfma_f32_32x32x16_bf16(A0.v, vf2, o_acc[1], 0, 0, 0);
            o_acc[1] = __builtin_amdgcn_mfma_f32_32x32x16_bf16(A1.v, vf3, o_acc[1], 0, 0, 0);
            __builtin_amdgcn_s_setprio(0);
        }

        // ---- advance to next needed tile (wave-uniform SALU, no sync) ----
        k0 += TK;
        while (k0 < SS && !need_w_f(k0)) k0 += TK;
    }

    // ---- finish: psum halves -> full row sums, normalize, store ----
    psum += __shfl_xor(psum, 32, 64);
#pragma unroll
    for (int r = 0; r < 16; ++r) {
        const int q_loc = (r & 3) + 8 * (r >> 2) + 4 * hi2;
        const float tv = __shfl(psum, q_loc, 64);
        const float iv = 1.f / tv;
        float* dst = O + pbase + (size_t)(qw0 + q_loc) * DD + l31;
#pragma unroll
        for (int ntd = 0; ntd < 2; ++ntd)
            dst[ntd * 32] = o_acc[ntd][r] * iv;
    }
}

extern "C" void kernel_launch(void* const* d_in, const int* in_sizes, int n_in,
                              void* d_out, int out_size, void* d_ws, size_t ws_size,
                              hipStream_t stream) {
    const float* q = (const float*)d_in[0];
    const float* k = (const float*)d_in[1];
    const float* v = (const float*)d_in[2];
    float* o = (float*)d_out;

    const size_t NE = 7864320ULL;          // B*H*S*D
    ushort* Kb  = (ushort*)d_ws;
    ushort* Vtb = Kb + NE;                 // 31.5 MB workspace

    prepass8<<<dim3(5760), 256, 0, stream>>>(k, v, Kb, Vtb);
    omni_attn16<<<dim3(NITEMS), 256, 0, stream>>>(q, Kb, Vtb, o);
}

// Round 22
// 99.716 us; speedup vs baseline: 1.3961x; 1.3961x over previous
//
#include <hip/hip_runtime.h>
#include <hip/hip_bf16.h>
#include <math.h>

// OmniAttentionMechanism: flex-attention, mixed t2i/lm/mmu mask.
// B=6 (b0,b1: t2i pe=80/100; b2,b3: lm; b4,b5: mmu kv<1027), H=16, S=1280, D=64. fp32 I/O.
//
// Round 19 (on R15 green, 94.7us): setprio KEPT (R17/R18 NaN'd with it removed —
//   volatile theory refuted by R18; the setprio side-effect fences are load-bearing
//   on this structure). Sync/sched structure byte-identical to R15.
//   Arithmetic-only deltas:
//     1. psum split into 2 accumulators (shorter serial add chain)
//     2. t2i mask hoist: qin per-lane once; kvi per-half-tile wave-uniform
//        (128/1152 are 32-aligned -> all-or-none) -> ~5 VALU/elem vs ~12.

#define SS 1280
#define DD 64
#define NH 16
#define TK 64
#define QB 128
#define NITEMS 960

typedef __attribute__((ext_vector_type(8))) short bf16x8;
typedef __attribute__((ext_vector_type(16))) float f32x16;

union UA { uint u[4]; bf16x8 v; };

__device__ inline uint pk2(float a, float b) {
    union { __hip_bfloat162 h; uint u; } cv;
    cv.h = __float22bfloat162_rn(float2{a, b});   // v_cvt_pk_bf16_f32
    return cv.u;
}

// volatile: convergent cross-lane op (and keep scheduling identical to R15)
__device__ inline void pl32(uint& a, uint& b) {
    asm volatile("v_permlane32_swap_b32 %0, %1" : "+v"(a), "+v"(b));
}

#define WAITVM2() asm volatile("s_waitcnt vmcnt(2)" ::: "memory")

// longest-first static item order
__device__ inline void decode_item(int i, int& b, int& h, int& qt) {
    if (i < 96)  { qt = 9; b = i / 16; h = i % 16; return; }                   // N=20
    i -= 96;
    if (i < 256) { b = i / 128; qt = 1 + (i % 128) / 16; h = i % 16; return; } // t2i qt1-8, N=18
    i -= 256;
    if (i < 32)  { b = 2 + i / 16; qt = 8; h = i % 16; return; }               // lm qt8, N=18
    i -= 32;
    if (i < 32)  { b = 4 + i / 16; qt = 8; h = i % 16; return; }               // mmu qt8, N=18
    i -= 32;
    if (i < 256) { b = 4 + i / 128; qt = (i % 128) / 16; h = i % 16; return; } // mmu qt0-7, N=17
    i -= 256;
    if (i < 224) { qt = 7 - i / 32; b = 2 + (i % 32) / 16; h = i % 16; return; } // lm qt7..1
    i -= 224;
    if (i < 32)  { b = 2 + i / 16; qt = 0; h = i % 16; return; }               // lm qt0, N=2
    i -= 32;
    b = i / 16; qt = 0; h = i % 16;                                            // t2i qt0, N=2
}

// ============ fused prepass: K->bf16 (gx<3840) | V->Vt[d][kv] bf16 (gx>=3840) ============
__global__ __launch_bounds__(256) void prepass8(
    const float* __restrict__ K, const float* __restrict__ V,
    ushort* __restrict__ Kb, ushort* __restrict__ Vtb)
{
    const int gx = blockIdx.x;
    const int t  = threadIdx.x;
    if (gx < 3840) {
        const size_t e = ((size_t)gx * 256 + t) * 8;
        const float4 a = *(const float4*)(K + e);
        const float4 c = *(const float4*)(K + e + 4);
        UA u;
        u.u[0] = pk2(a.x, a.y); u.u[1] = pk2(a.z, a.w);
        u.u[2] = pk2(c.x, c.y); u.u[3] = pk2(c.z, c.w);
        *(bf16x8*)(Kb + e) = u.v;
    } else {
        const int g   = gx - 3840;
        const int kvt = g % 20;
        const int p   = g / 20;
        __shared__ float T[64 * 67];
#pragma unroll
        for (int i = 0; i < 16; ++i) {
            const int idx = t + 256 * i;
            T[(idx >> 6) * 67 + (idx & 63)] = V[(size_t)p * (SS * DD) + (size_t)(kvt * 64) * DD + idx];
        }
        __syncthreads();
        ushort* dst = Vtb + (size_t)p * (DD * SS) + kvt * 64;
#pragma unroll
        for (int i = 0; i < 2; ++i) {
            const int c0 = t + 256 * i;
            const int d = c0 >> 3, kc = c0 & 7;
            UA u;
#pragma unroll
            for (int j = 0; j < 4; ++j)
                u.u[j] = pk2(T[(kc * 8 + 2 * j) * 67 + d], T[(kc * 8 + 2 * j + 1) * 67 + d]);
            *(bf16x8*)(dst + (size_t)d * SS + kc * 8) = u.v;
        }
    }
}

// ============================ main attention kernel ============================
__global__ __launch_bounds__(256) void omni_attn19(
    const float* __restrict__ Q, const ushort* __restrict__ Kb,
    const ushort* __restrict__ Vtb, float* __restrict__ O)
{
    int b, h, qt;
    decode_item(blockIdx.x, b, h, qt);     // longest-first dispatch order

    const int t   = threadIdx.x;
    const int w   = t >> 6;
    const int l   = t & 63;
    const int l31 = l & 31;
    const int hi2 = l >> 5;

    const int p   = b * NH + h;
    const int qb0 = qt * QB;
    const int qw0 = qb0 + w * 32;
    const int qr  = qw0 + l31;
    const size_t pbase = (size_t)p * (SS * DD);

    const int bt = (b < 2) ? 0 : (b < 4) ? 1 : 2;
    const int pe = (b == 0) ? 80 : (b == 1) ? 100 : 0;
    const int qmax_blk = qb0 + QB - 1;
    const int qmax_w   = qw0 + 31;
    const bool blk_img = (qb0 + QB - 1 >= 128) && (qb0 < 1152);
    const bool w_img   = (qw0 >= 128) && (qw0 < 1152);
    const bool qin     = (qr >= 128) && (qr < 1152);   // hoisted per-lane image test

    __shared__ char smem[3 * 8192];        // 3 K-only buffers

    const float scale = 0.125f * 1.44269504088896340736f;

    // per-thread K staging offsets (inverse-swizzled source)
    int koff[2];
#pragma unroll
    for (int rd = 0; rd < 2; ++rd) {
        const int ci  = rd * 256 + w * 64 + l;
        const int row = ci >> 3, cc = ci & 7;
        koff[rd] = row * DD + (cc ^ (row & 7)) * 8;
    }

    // ---- Q fragments, scale folded in (p = exp2(K·(Q*scale))) ----
    bf16x8 qf[4];
#pragma unroll
    for (int ks = 0; ks < 4; ++ks) {
        const float* src = Q + pbase + (size_t)qr * DD + ks * 16 + hi2 * 8;
        const float4 a = *(const float4*)(src);
        const float4 c = *(const float4*)(src + 4);
        UA u;
        u.u[0] = pk2(a.x * scale, a.y * scale); u.u[1] = pk2(a.z * scale, a.w * scale);
        u.u[2] = pk2(c.x * scale, c.y * scale); u.u[3] = pk2(c.z * scale, c.w * scale);
        qf[ks] = u.v;
    }

    f32x16 o_acc[2];
#pragma unroll
    for (int ntd = 0; ntd < 2; ++ntd)
#pragma unroll
        for (int r = 0; r < 16; ++r) o_acc[ntd][r] = 0.f;
    float psum0 = 0.f, psum1 = 0.f;

    auto need_blk = [&](int k0) -> bool {
        if (bt == 0) return (k0 <= qmax_blk) || (blk_img && k0 >= 128 && k0 < 1152);
        if (bt == 1) return (k0 <= qmax_blk);
        return (k0 <= qmax_blk) || (k0 < 1027);
    };
    auto next_tile = [&](int k) -> int {
        k += TK;
        while (k < SS && !need_blk(k)) k += TK;
        return k;
    };
    auto stageK = [&](int bsel, int k0s) {
        char* buf = smem + bsel * 8192;
        const ushort* Kp = Kb + pbase + (size_t)k0s * DD;
#pragma unroll
        for (int rd = 0; rd < 2; ++rd) {
            char* lb = buf + (rd * 256 + w * 64) * 16;
            __builtin_amdgcn_global_load_lds(
                (const __attribute__((address_space(1))) void*)(Kp + koff[rd]),
                (__attribute__((address_space(3))) void*)lb, 16, 0, 0);
        }
    };

    // V per-lane base rows (d = l31 and d = 32+l31), col offset hi2*8
    const ushort* vrow0 = Vtb + pbase + (size_t)l31 * SS + hi2 * 8;
    const ushort* vrow1 = vrow0 + 32 * SS;

    // ---- 3-buffer, 2-deep pipeline; stage issued post-compute; vmcnt(2)/tile ----
    int ka = 0, cur = 0;
    int kb = next_tile(0);                 // >= 2 tiles always exist
    int kc = (kb < SS) ? next_tile(kb) : SS;
    stageK(0, ka);
    stageK(1, kb);
    WAITVM2();                             // K(0) landed; K(1) in flight
    __builtin_amdgcn_s_barrier();
    __builtin_amdgcn_sched_barrier(0);

    while (true) {
        const int k0 = ka;
        const bool kv_img = (k0 >= 128) && (k0 < 1152);
        bool need_w, full_w;
        if (bt == 0) {
            need_w = (k0 <= qmax_w) || (w_img && kv_img);
            full_w = ((k0 >= pe) && (k0 + 63 <= qw0)) || (w_img && kv_img);
        } else if (bt == 1) {
            need_w = (k0 <= qmax_w);
            full_w = (k0 + 63 <= qw0);
        } else {
            need_w = (k0 <= qmax_w) || (k0 < 1027);
            full_w = (k0 + 63 <= qw0) || (k0 + 63 < 1027);
        }

        if (need_w) {
            char* cbuf = smem + cur * 8192;
#pragma unroll
            for (int nt = 0; nt < 2; ++nt) {
                // ---- V fragments for this kv half: 4 x bf16x8 (16 regs) ----
                const int vb = k0 + nt * 32;
                bf16x8 vfn[4];
                vfn[0] = *(const bf16x8*)(vrow0 + vb);
                vfn[1] = *(const bf16x8*)(vrow0 + vb + 16);
                vfn[2] = *(const bf16x8*)(vrow1 + vb);
                vfn[3] = *(const bf16x8*)(vrow1 + vb + 16);

                // ---- QK^T swapped: S[kv][q], A = K rows (LDS), B = Q cols ----
                f32x16 s;
#pragma unroll
                for (int r = 0; r < 16; ++r) s[r] = 0.f;
                __builtin_amdgcn_s_setprio(1);
#pragma unroll
                for (int ksd = 0; ksd < 4; ++ksd) {
                    const int row = nt * 32 + l31;
                    int off = row * 128 + ksd * 32 + hi2 * 16;
                    off ^= (row & 7) << 4;
                    const bf16x8 kf = *(const bf16x8*)(cbuf + off);
                    s = __builtin_amdgcn_mfma_f32_32x32x16_bf16(kf, qf[ksd], s, 0, 0, 0);
                }
                __builtin_amdgcn_s_setprio(0);

                // ---- mask + exp2 (scale pre-folded; qin/kvi hoisted) ----
                const int c0k = k0 + nt * 32;
                const bool kvi = (c0k >= 128) && (c0k < 1152);  // 32-aligned: all-or-none
                uint c[8];
#pragma unroll
                for (int i = 0; i < 8; ++i) {
                    float pa, pb;
                    if (full_w) {
                        pa = __builtin_amdgcn_exp2f(s[2 * i]);
                        pb = __builtin_amdgcn_exp2f(s[2 * i + 1]);
                    } else {
                        const int r0i = 2 * i, r1i = 2 * i + 1;
                        const int kva = c0k + (r0i & 3) + 8 * (r0i >> 2) + 4 * hi2;
                        const int kvb = c0k + (r1i & 3) + 8 * (r1i >> 2) + 4 * hi2;
                        bool aa, ab;
                        if (bt == 0) {
                            aa = (qr == kva) | ((kva >= pe) & (qr >= kva)) | (qin & kvi);
                            ab = (qr == kvb) | ((kvb >= pe) & (qr >= kvb)) | (qin & kvi);
                        } else if (bt == 1) {
                            aa = (qr >= kva); ab = (qr >= kvb);
                        } else {
                            aa = (qr >= kva) | (kva < 1027);
                            ab = (qr >= kvb) | (kvb < 1027);
                        }
                        pa = aa ? __builtin_amdgcn_exp2f(s[2 * i]) : 0.f;
                        pb = ab ? __builtin_amdgcn_exp2f(s[2 * i + 1]) : 0.f;
                    }
                    if (i & 1) psum1 += pa + pb; else psum0 += pa + pb;
                    c[i] = pk2(pa, pb);
                }

                // ---- P half-exchange: 4x v_permlane32_swap ----
                UA A0, A1;
                {
                    uint a0 = c[0], b0 = c[2]; pl32(a0, b0);
                    uint a1 = c[1], b1 = c[3]; pl32(a1, b1);
                    A0.u[0] = a0; A0.u[1] = a1; A0.u[2] = b0; A0.u[3] = b1;
                    uint a2 = c[4], b2 = c[6]; pl32(a2, b2);
                    uint a3 = c[5], b3 = c[7]; pl32(a3, b3);
                    A1.u[0] = a2; A1.u[1] = a3; A1.u[2] = b2; A1.u[3] = b3;
                }

                // ---- PV: o[q][d] += P * V ; B-frags from V registers (R15 order) ----
                __builtin_amdgcn_s_setprio(1);
                o_acc[0] = __builtin_amdgcn_mfma_f32_32x32x16_bf16(A0.v, vfn[0], o_acc[0], 0, 0, 0);
                o_acc[0] = __builtin_amdgcn_mfma_f32_32x32x16_bf16(A1.v, vfn[1], o_acc[0], 0, 0, 0);
                o_acc[1] = __builtin_amdgcn_mfma_f32_32x32x16_bf16(A0.v, vfn[2], o_acc[1], 0, 0, 0);
                o_acc[1] = __builtin_amdgcn_mfma_f32_32x32x16_bf16(A1.v, vfn[3], o_acc[1], 0, 0, 0);
                __builtin_amdgcn_s_setprio(0);
            }
        }

        // ---- issue stage(i+2) LAST; ledger = 2 in-flight stages ----
        stageK((cur + 2) % 3, (kc < SS) ? kc : 0);   // dummy at tail keeps ledger uniform
        WAITVM2();                          // K(i+1) confirmed; K(i+2) in flight
        __builtin_amdgcn_s_barrier();
        __builtin_amdgcn_sched_barrier(0);
        if (kb >= SS) break;
        ka = kb; kb = kc; kc = (kc < SS) ? next_tile(kc) : SS;
        cur = (cur + 1) % 3;
    }

    // ---- finish: psum halves -> full row sums, normalize, store ----
    float psum = psum0 + psum1;
    psum += __shfl_xor(psum, 32, 64);
#pragma unroll
    for (int r = 0; r < 16; ++r) {
        const int q_loc = (r & 3) + 8 * (r >> 2) + 4 * hi2;
        const float tv = __shfl(psum, q_loc, 64);
        const float iv = 1.f / tv;
        float* dst = O + pbase + (size_t)(qw0 + q_loc) * DD + l31;
#pragma unroll
        for (int ntd = 0; ntd < 2; ++ntd)
            dst[ntd * 32] = o_acc[ntd][r] * iv;
    }
}

extern "C" void kernel_launch(void* const* d_in, const int* in_sizes, int n_in,
                              void* d_out, int out_size, void* d_ws, size_t ws_size,
                              hipStream_t stream) {
    const float* q = (const float*)d_in[0];
    const float* k = (const float*)d_in[1];
    const float* v = (const float*)d_in[2];
    float* o = (float*)d_out;

    const size_t NE = 7864320ULL;          // B*H*S*D
    ushort* Kb  = (ushort*)d_ws;
    ushort* Vtb = Kb + NE;                 // 31.5 MB workspace

    prepass8<<<dim3(5760), 256, 0, stream>>>(k, v, Kb, Vtb);
    omni_attn19<<<dim3(NITEMS), 256, 0, stream>>>(q, Kb, Vtb, o);
}